// Round 9
// baseline (298.367 us; speedup 1.0000x reference)
//
#include <hip/hip_runtime.h>

// LSHAttention == plain MHA (sort+full-softmax+unsort is permutation-invariant).
// bf16 MFMA pipeline: prep(cast/transpose) -> qkv GEMM -> flash MFMA attn -> out GEMM.
// B=2, L=2048, F=1024, H=16, D=64. I/O fp32; internals bf16 with fp32 accum.
// Attn v6 = v4 (64q x 64k wave-iters, S^T trick, split-K, ones-column psum)
// with LDS 64->48 KB: K double-buffered (lazy reads), V single-buffered
// (vf forced into regs before a 2nd barrier, then restaged). 3 blocks/CU.

#define B_ 2
#define L_ 2048
#define F_ 1024
#define H_ 16
#define D_ 64
#define M_ 4096

typedef unsigned short u16;
typedef unsigned int   u32;
typedef __bf16 bf16x8 __attribute__((ext_vector_type(8)));
typedef float  f32x4  __attribute__((ext_vector_type(4)));

__device__ __forceinline__ u16 f2bf(float f) {
    __bf16 h = (__bf16)f;                       // native RNE cvt on gfx950
    return __builtin_bit_cast(u16, h);
}

// async global->LDS, 16B per lane. LDS dest = wave-uniform base + lane*16.
__device__ __forceinline__ void glds16(const void* g, void* l) {
    __builtin_amdgcn_global_load_lds(
        (const __attribute__((address_space(1))) u32*)g,
        (__attribute__((address_space(3))) u32*)l, 16, 0, 0);
}

#define MFMA16(a, b, c) __builtin_amdgcn_mfma_f32_16x16x32_bf16(a, b, c, 0, 0, 0)

// ---------------------------------------------------------------------------
// Prep: cast x -> bf16
// ---------------------------------------------------------------------------
__global__ __launch_bounds__(256) void cast_x(const float* __restrict__ x, u16* __restrict__ xb) {
    int i0 = blockIdx.x * 256 + threadIdx.x;
    #pragma unroll
    for (int r = 0; r < 4; ++r) {
        int i = i0 + r * 262144;
        float4 v = ((const float4*)x)[i];
        ushort4 o; o.x = f2bf(v.x); o.y = f2bf(v.y); o.z = f2bf(v.z); o.w = f2bf(v.w);
        ((ushort4*)xb)[i] = o;
    }
}

// Prep: transpose+cast all three weights in one launch.
__global__ __launch_bounds__(256) void tr_all(
    const float* __restrict__ Wqk, const float* __restrict__ Wv,
    const float* __restrict__ Wo, u16* __restrict__ Wt, u16* __restrict__ Wot)
{
    __shared__ float tile[32][33];
    const int z = blockIdx.z;
    const float* src; u16* dst; int N;
    if (z == 0)      { src = Wqk; dst = Wt;                       N = 2048; }
    else if (z == 1) { src = Wv;  dst = Wt + (size_t)2048 * 1024; N = 1024; }
    else             { src = Wo;  dst = Wot;                      N = 1024; }
    int n0 = blockIdx.x * 32, k0 = blockIdx.y * 32;
    if (n0 >= N) return;
    int tx = threadIdx.x & 31, ty = threadIdx.x >> 5;
    #pragma unroll
    for (int i = 0; i < 4; ++i) {
        int k = ty + i * 8;
        tile[k][tx] = src[(size_t)(k0 + k) * N + n0 + tx];
    }
    __syncthreads();
    #pragma unroll
    for (int i = 0; i < 4; ++i) {
        int n = ty + i * 8;
        dst[(size_t)(n0 + n) * 1024 + k0 + tx] = f2bf(tile[tx][n]);
    }
}

// ---------------------------------------------------------------------------
// MFMA GEMM K-loop (m97 structure): C[128][128], A[m][k], Bt[n][k], BK=32.
// ---------------------------------------------------------------------------
__device__ __forceinline__ void gemm_loop(
    const u16* __restrict__ A, const u16* __restrict__ Bt,
    size_t m0, size_t n0, u16* As, u16* Bs, int t, f32x4 acc[4][4])
{
    const int w = t >> 6, lane = t & 63, ml = lane & 15, quad = lane >> 4;
    const int mw = (w >> 1) * 64, nw = (w & 1) * 64;
    const int srow = (lane >> 2), schunk = (lane & 3) * 8;

    for (int k0 = 0; k0 < 1024; k0 += 32) {
        __syncthreads();
        #pragma unroll
        for (int i = 0; i < 2; ++i) {
            int row = w * 32 + i * 16 + srow;
            glds16(A  + (m0 + row) * 1024 + k0 + schunk, As + (w * 32 + i * 16) * 32);
            glds16(Bt + (n0 + row) * 1024 + k0 + schunk, Bs + (w * 32 + i * 16) * 32);
        }
        __syncthreads();
        bf16x8 af[4], bf_[4];
        #pragma unroll
        for (int mt = 0; mt < 4; ++mt)
            af[mt] = *(const bf16x8*)(As + (mw + mt * 16 + ml) * 32 + quad * 8);
        #pragma unroll
        for (int nt = 0; nt < 4; ++nt)
            bf_[nt] = *(const bf16x8*)(Bs + (nw + nt * 16 + ml) * 32 + quad * 8);
        #pragma unroll
        for (int mt = 0; mt < 4; ++mt)
            #pragma unroll
            for (int nt = 0; nt < 4; ++nt)
                acc[mt][nt] = MFMA16(af[mt], bf_[nt], acc[mt][nt]);
    }
}

// QKV GEMM: xb[4096][1024] @ Wt[3072][1024]^T. Epilogue scatters:
// cols 0..1023 -> Qb (x 0.125*log2e), 1024..2047 -> Kb, 2048..3071 -> Vt
// transposed [b,h,d,l] with l column-permuted within each 64-block:
// group g=(l>>2)&15 -> (g&8)*4 + (g&3)*8 + (g&4)  (PV b128 frags).
__global__ __launch_bounds__(256) void qkv_gemm(
    const u16* __restrict__ xb, const u16* __restrict__ Wt,
    const float* __restrict__ bqk, const float* __restrict__ bv,
    u16* __restrict__ Qb, u16* __restrict__ Kb, u16* __restrict__ Vt)
{
    __shared__ __align__(16) u16 As[128 * 32];
    __shared__ __align__(16) u16 Bs[128 * 32];
    const int t = threadIdx.x;
    const size_t m0 = blockIdx.y * 128, n0 = blockIdx.x * 128;
    f32x4 acc[4][4] = {};
    gemm_loop(xb, Wt, m0, n0, As, Bs, t, acc);

    const int w = t >> 6, lane = t & 63, ml = lane & 15, quad = lane >> 4;
    const int mw = (w >> 1) * 64, nw = (w & 1) * 64;
    const int seg = (int)(n0 >> 10);                   // 0=Q 1=K 2=V (block-uniform)

    #pragma unroll
    for (int mt = 0; mt < 4; ++mt) {
        #pragma unroll
        for (int nt = 0; nt < 4; ++nt) {
            f32x4 a = acc[mt][nt];
            int c = (int)n0 + nw + nt * 16 + ml;
            int mbase = (int)m0 + mw + mt * 16 + quad * 4;
            if (seg == 2) {
                int cv = c - 2048, h = cv >> 6, d = cv & 63;
                float bias = bv[cv];
                int bb = mbase >> 11, l0 = mbase & (L_ - 1);
                int g = (l0 >> 2) & 15;
                int col = (l0 & ~63) + ((g & 8) << 2) + ((g & 3) << 3) + (g & 4);
                ushort4 pk;
                pk.x = f2bf(a[0] + bias); pk.y = f2bf(a[1] + bias);
                pk.z = f2bf(a[2] + bias); pk.w = f2bf(a[3] + bias);
                *(ushort4*)&Vt[(((size_t)(bb * H_ + h)) * D_ + d) * L_ + col] = pk;
            } else {
                float bias = bqk[c];
                // Q scale: 1/sqrt(64) * log2(e)  (attn uses exp2)
                float sc = (seg == 0) ? 0.1803368801111244f : 1.0f;
                u16* dst = (seg == 0) ? Qb : Kb;
                int cc = c & 1023, h = cc >> 6, d = cc & 63;
                #pragma unroll
                for (int reg = 0; reg < 4; ++reg) {
                    int m = mbase + reg, bb = m >> 11, l = m & (L_ - 1);
                    dst[(((size_t)(bb * H_ + h)) * L_ + l) * D_ + d] = f2bf((a[reg] + bias) * sc);
                }
            }
        }
    }
}

// out GEMM: 64x128 tiles (grid 512 = 2 blocks/CU).
__global__ __launch_bounds__(256) void out_gemm(
    const u16* __restrict__ Ob, const u16* __restrict__ Wot,
    const float* __restrict__ bo, float* __restrict__ out)
{
    __shared__ __align__(16) u16 As[64 * 32];
    __shared__ __align__(16) u16 Bs[128 * 32];
    const int t = threadIdx.x, w = t >> 6, lane = t & 63;
    const int ml = lane & 15, quad = lane >> 4;
    const int mw = (w >> 1) * 32, nw = (w & 1) * 64;
    const size_t m0 = blockIdx.y * 64, n0 = blockIdx.x * 128;
    const int srow = lane >> 2, schunk = (lane & 3) * 8;

    f32x4 acc[2][4] = {};
    for (int k0 = 0; k0 < 1024; k0 += 32) {
        __syncthreads();
        {
            int row = w * 16 + srow;
            glds16(Ob + (m0 + row) * 1024 + k0 + schunk, As + (w * 16) * 32);
        }
        #pragma unroll
        for (int i = 0; i < 2; ++i) {
            int row = w * 32 + i * 16 + srow;
            glds16(Wot + (n0 + row) * 1024 + k0 + schunk, Bs + (w * 32 + i * 16) * 32);
        }
        __syncthreads();
        bf16x8 af[2], bf_[4];
        #pragma unroll
        for (int mt = 0; mt < 2; ++mt)
            af[mt] = *(const bf16x8*)(As + (mw + mt * 16 + ml) * 32 + quad * 8);
        #pragma unroll
        for (int nt = 0; nt < 4; ++nt)
            bf_[nt] = *(const bf16x8*)(Bs + (nw + nt * 16 + ml) * 32 + quad * 8);
        #pragma unroll
        for (int mt = 0; mt < 2; ++mt)
            #pragma unroll
            for (int nt = 0; nt < 4; ++nt)
                acc[mt][nt] = MFMA16(af[mt], bf_[nt], acc[mt][nt]);
    }

    #pragma unroll
    for (int mt = 0; mt < 2; ++mt)
        #pragma unroll
        for (int nt = 0; nt < 4; ++nt) {
            int c = (int)n0 + nw + nt * 16 + ml;
            int mbase = (int)m0 + mw + mt * 16 + quad * 4;
            float bias = bo[c];
            #pragma unroll
            for (int reg = 0; reg < 4; ++reg)
                out[(size_t)(mbase + reg) * F_ + c] = acc[mt][nt][reg] + bias;
        }
}

// ---------------------------------------------------------------------------
// Attention v6: v4 structure (64q x 64k per wave-iter), LDS 48 KB.
// Block = 4 waves: wave w -> half = w>>1 (keys half*1024..+1023, 16 tiles
// of 64), qsel = w&1 (queries qt*128+qsel*64). Grid (16,16,2) = 512 blocks;
// 48 KB LDS -> 3 blocks/CU = 12 waves/CU.
// K double-buffered (kf reads lazy, during compute); V single-buffered:
// vf forced into regs between two barriers, then V restaged (overlapped
// with compute, drains at next iter's first barrier).
// S^T = K*Q^T; P = exp2(S^T) in-register == PV A-frag; psum via ones MFMA.
// ---------------------------------------------------------------------------
__global__ __launch_bounds__(256, 3) void attn_mfma(
    const u16* __restrict__ Qb, const u16* __restrict__ Kb,
    const u16* __restrict__ Vt, u16* __restrict__ Ob)
{
    __shared__ __align__(16) u16 smem[24576];          // 48 KB: K[2][2][4096] | V[2][4096]

    const int t = threadIdx.x, w = t >> 6, lane = t & 63;
    const int ml = lane & 15, quad = lane >> 4;
    const int half = w >> 1, qsel = w & 1;
    const int qt = blockIdx.x, h = blockIdx.y, b = blockIdx.z;
    const int qbase = qt * 128 + qsel * 64;
    const size_t hoff = ((size_t)(b * H_ + h)) * (size_t)L_ * D_;
    const u16* Qg = Qb + hoff;
    const u16* Kg = Kb + hoff + (size_t)half * 1024 * 64;   // this half's keys
    const u16* Vg = Vt + hoff;                         // [d][l_perm64], ld = 2048
    u16* Kst = smem + half * 8192;                     // [dbuf][4096]
    u16* Vst = smem + 16384 + half * 4096;             // [4096] single-buffer

    // Q fragments (B-operand of S^T), hoisted: lane ml = query row
    bf16x8 qf[4][2];
    #pragma unroll
    for (int m2 = 0; m2 < 4; ++m2)
        #pragma unroll
        for (int k2 = 0; k2 < 2; ++k2)
            qf[m2][k2] = *(const bf16x8*)(Qg + (size_t)(qbase + m2 * 16 + ml) * 64 + k2 * 32 + quad * 8);

    const int srow = lane >> 3, sch = lane & 7;
    auto stageK = [&](int i, int d) {                  // qsel pair: 32 rows each
        #pragma unroll
        for (int ii = 0; ii < 4; ++ii) {
            int row = qsel * 32 + ii * 8 + srow;
            int ch = sch ^ (row & 7);
            glds16(Kg + (size_t)(i * 64 + row) * 64 + ch * 8,
                   Kst + d * 4096 + (qsel * 32 + ii * 8) * 64);
        }
    };
    auto stageV = [&](int i) {                         // V rows are d (0..63)
        #pragma unroll
        for (int ii = 0; ii < 4; ++ii) {
            int row = qsel * 32 + ii * 8 + srow;
            int ch = sch ^ (row & 7);
            glds16(Vg + (size_t)row * L_ + half * 1024 + i * 64 + ch * 8,
                   Vst + (qsel * 32 + ii * 8) * 64);
        }
    };

    bf16x8 vone;
    #pragma unroll
    for (int j = 0; j < 8; ++j) vone[j] = (__bf16)1.0f;

    f32x4 oacc[4][5] = {};                             // [m2][d0..3, psum]

    stageK(0, 0); stageV(0);
    for (int i = 0; i < 16; ++i) {
        __syncthreads();                               // stage(i) landed (vmcnt drain)

        // vf: force all 8 b128 reads now (single V buffer)
        bf16x8 vf[4][2];
        #pragma unroll
        for (int dt = 0; dt < 4; ++dt) {
            int row = dt * 16 + ml;
            #pragma unroll
            for (int tp = 0; tp < 2; ++tp)
                vf[dt][tp] = *(const bf16x8*)(Vst + row * 64 + (((tp * 4 + quad) ^ (row & 7)) << 3));
        }
        __syncthreads();                               // vf in regs; V buffer free

        if (i < 15) { stageK(i + 1, (i + 1) & 1); stageV(i + 1); }  // overlaps compute

        const u16* Kl = Kst + (i & 1) * 4096;
        bf16x8 kf[4][2];
        #pragma unroll
        for (int t4 = 0; t4 < 4; ++t4) {
            int row = t4 * 16 + ml;
            #pragma unroll
            for (int k2 = 0; k2 < 2; ++k2)
                kf[t4][k2] = *(const bf16x8*)(Kl + row * 64 + (((k2 * 4 + quad) ^ (row & 7)) << 3));
        }

        #pragma unroll
        for (int m2 = 0; m2 < 4; ++m2) {
            f32x4 sacc[4] = {};
            #pragma unroll
            for (int k2 = 0; k2 < 2; ++k2)
                #pragma unroll
                for (int t4 = 0; t4 < 4; ++t4)
                    sacc[t4] = MFMA16(kf[t4][k2], qf[m2][k2], sacc[t4]);

            bf16x8 ap[2];
            #pragma unroll
            for (int t4 = 0; t4 < 4; ++t4)
                #pragma unroll
                for (int r = 0; r < 4; ++r)
                    ap[t4 >> 1][(t4 & 1) * 4 + r] = (__bf16)exp2f(sacc[t4][r]);

            #pragma unroll
            for (int tp = 0; tp < 2; ++tp) {
                #pragma unroll
                for (int dt = 0; dt < 4; ++dt)
                    oacc[m2][dt] = MFMA16(ap[tp], vf[dt][tp], oacc[m2][dt]);
                oacc[m2][4] = MFMA16(ap[tp], vone, oacc[m2][4]);   // row sums
            }
        }
    }

    // combine halves through LDS (pure additive: no-max softmax partials)
    __syncthreads();
    float* Fb = (float*)smem;                          // 40 KB < 48 KB
    if (half == 1) {
        #pragma unroll
        for (int m2 = 0; m2 < 4; ++m2)
            #pragma unroll
            for (int f = 0; f < 5; ++f)
                *(f32x4*)&Fb[(((qsel * 4 + m2) * 5 + f) * 64 + lane) * 4] = oacc[m2][f];
    }
    __syncthreads();
    if (half == 0) {
        #pragma unroll
        for (int m2 = 0; m2 < 4; ++m2)
            #pragma unroll
            for (int f = 0; f < 5; ++f)
                oacc[m2][f] += *(const f32x4*)&Fb[(((qsel * 4 + m2) * 5 + f) * 64 + lane) * 4];

        #pragma unroll
        for (int m2 = 0; m2 < 4; ++m2)
            #pragma unroll
            for (int r = 0; r < 4; ++r) {
                float il = 1.0f / oacc[m2][4][r];      // psum, layout-aligned
                int row = b * L_ + qbase + m2 * 16 + quad * 4 + r;
                #pragma unroll
                for (int dt = 0; dt < 4; ++dt) {
                    int c = h * 64 + dt * 16 + ml;
                    Ob[(size_t)row * F_ + c] = f2bf(oacc[m2][dt][r] * il);
                }
            }
    }
}

// ---------------------------------------------------------------------------
extern "C" void kernel_launch(void* const* d_in, const int* in_sizes, int n_in,
                              void* d_out, int out_size, void* d_ws, size_t ws_size,
                              hipStream_t stream)
{
    const float* x   = (const float*)d_in[0];
    const float* Wqk = (const float*)d_in[1];
    const float* bqk = (const float*)d_in[2];
    const float* Wv  = (const float*)d_in[3];
    const float* bv  = (const float*)d_in[4];
    const float* Wo  = (const float*)d_in[5];
    const float* bo  = (const float*)d_in[6];
    // d_in[7] = R: unused (LSH sort is a mathematical no-op).
    (void)in_sizes; (void)n_in; (void)out_size; (void)ws_size;
    float* out = (float*)d_out;

    u16* w16 = (u16*)d_ws;
    u16* xb  = w16;                   // 4096*1024
    u16* Wt  = xb  + 4194304;         // 3072*1024  (Wqk^T | Wv^T)
    u16* Wot = Wt  + 3145728;         // 1024*1024
    u16* Qb  = Wot + 1048576;         // [b,h,l,d]  (x 0.125*log2e)
    u16* Kb  = Qb  + 4194304;         // [b,h,l,d]
    u16* Vtw = Kb  + 4194304;         // [b,h,d,l_perm64]
    u16* Ob  = Vtw + 4194304;         // [4096][1024]

    cast_x<<<1024, 256, 0, stream>>>(x, xb);
    tr_all<<<dim3(64, 32, 3), 256, 0, stream>>>(Wqk, Wv, Wo, Wt, Wot);
    qkv_gemm<<<dim3(24, 32), 256, 0, stream>>>(xb, Wt, bqk, bv, Qb, Kb, Vtw);
    attn_mfma<<<dim3(16, 16, 2), 256, 0, stream>>>(Qb, Kb, Vtw, Ob);
    out_gemm<<<dim3(8, 64), 256, 0, stream>>>(Ob, Wot, bo, out);
}

// Round 10
// 191.740 us; speedup vs baseline: 1.5561x; 1.5561x over previous
//
#include <hip/hip_runtime.h>

// LSHAttention == plain MHA (sort+full-softmax+unsort is permutation-invariant).
// bf16 MFMA pipeline: prep(cast+transpose, fused) -> qkv GEMM -> flash MFMA attn
// -> out GEMM. B=2, L=2048, F=1024, H=16, D=64. I/O fp32; internals bf16/fp32 acc.
// Attn = r7 "v4" (known-good 59us): 64q x 64k wave-iters, S^T = K*Q^T trick
// (P = exp2(S^T) in-register == PV A-fragment), in-block split-K, psum via
// ones-column MFMA, K/V dbuf glds16, one barrier/iter.
// REGISTER NOTE (r9 failure): unified VGPR+AGPR ~200 regs -> MUST be
// __launch_bounds__(256,2); a (256,3) cap (170) spills ~600 MB to scratch.

#define B_ 2
#define L_ 2048
#define F_ 1024
#define H_ 16
#define D_ 64
#define M_ 4096

typedef unsigned short u16;
typedef unsigned int   u32;
typedef __bf16 bf16x8 __attribute__((ext_vector_type(8)));
typedef float  f32x4  __attribute__((ext_vector_type(4)));

__device__ __forceinline__ u16 f2bf(float f) {
    __bf16 h = (__bf16)f;                       // native RNE cvt on gfx950
    return __builtin_bit_cast(u16, h);
}

// async global->LDS, 16B per lane. LDS dest = wave-uniform base + lane*16.
__device__ __forceinline__ void glds16(const void* g, void* l) {
    __builtin_amdgcn_global_load_lds(
        (const __attribute__((address_space(1))) u32*)g,
        (__attribute__((address_space(3))) u32*)l, 16, 0, 0);
}

#define MFMA16(a, b, c) __builtin_amdgcn_mfma_f32_16x16x32_bf16(a, b, c, 0, 0, 0)

// ---------------------------------------------------------------------------
// Fused prep: z=0 -> cast x to bf16 (2048 blocks' worth via x,y);
// z=1 -> Wqk^T, z=2 -> Wv^T, z=3 -> Wo^T (transpose+cast).
// ---------------------------------------------------------------------------
__global__ __launch_bounds__(256) void prep(
    const float* __restrict__ x, const float* __restrict__ Wqk,
    const float* __restrict__ Wv, const float* __restrict__ Wo,
    u16* __restrict__ xb, u16* __restrict__ Wt, u16* __restrict__ Wot)
{
    const int z = blockIdx.z;
    if (z == 0) {                                      // cast: 64x32 blocks
        int bid = blockIdx.x + blockIdx.y * 64;        // 0..2047
        int i0 = bid * 512 + threadIdx.x;
        #pragma unroll
        for (int r = 0; r < 2; ++r) {
            int i = i0 + r * 256;                      // 2048*512 = 1048576 f4
            float4 v = ((const float4*)x)[i];
            ushort4 o; o.x = f2bf(v.x); o.y = f2bf(v.y); o.z = f2bf(v.z); o.w = f2bf(v.w);
            ((ushort4*)xb)[i] = o;
        }
        return;
    }
    __shared__ float tile[32][33];
    const float* src; u16* dst; int N;
    if (z == 1)      { src = Wqk; dst = Wt;                       N = 2048; }
    else if (z == 2) { src = Wv;  dst = Wt + (size_t)2048 * 1024; N = 1024; }
    else             { src = Wo;  dst = Wot;                      N = 1024; }
    int n0 = blockIdx.x * 32, k0 = blockIdx.y * 32;
    if (n0 >= N) return;
    int tx = threadIdx.x & 31, ty = threadIdx.x >> 5;
    #pragma unroll
    for (int i = 0; i < 4; ++i) {
        int k = ty + i * 8;
        tile[k][tx] = src[(size_t)(k0 + k) * N + n0 + tx];
    }
    __syncthreads();
    #pragma unroll
    for (int i = 0; i < 4; ++i) {
        int n = ty + i * 8;
        dst[(size_t)(n0 + n) * 1024 + k0 + tx] = f2bf(tile[tx][n]);
    }
}

// ---------------------------------------------------------------------------
// MFMA GEMM K-loop (m97 structure): C[128][128], A[m][k], Bt[n][k], BK=32.
// ---------------------------------------------------------------------------
__device__ __forceinline__ void gemm_loop(
    const u16* __restrict__ A, const u16* __restrict__ Bt,
    size_t m0, size_t n0, u16* As, u16* Bs, int t, f32x4 acc[4][4])
{
    const int w = t >> 6, lane = t & 63, ml = lane & 15, quad = lane >> 4;
    const int mw = (w >> 1) * 64, nw = (w & 1) * 64;
    const int srow = (lane >> 2), schunk = (lane & 3) * 8;

    for (int k0 = 0; k0 < 1024; k0 += 32) {
        __syncthreads();
        #pragma unroll
        for (int i = 0; i < 2; ++i) {
            int row = w * 32 + i * 16 + srow;
            glds16(A  + (m0 + row) * 1024 + k0 + schunk, As + (w * 32 + i * 16) * 32);
            glds16(Bt + (n0 + row) * 1024 + k0 + schunk, Bs + (w * 32 + i * 16) * 32);
        }
        __syncthreads();
        bf16x8 af[4], bf_[4];
        #pragma unroll
        for (int mt = 0; mt < 4; ++mt)
            af[mt] = *(const bf16x8*)(As + (mw + mt * 16 + ml) * 32 + quad * 8);
        #pragma unroll
        for (int nt = 0; nt < 4; ++nt)
            bf_[nt] = *(const bf16x8*)(Bs + (nw + nt * 16 + ml) * 32 + quad * 8);
        #pragma unroll
        for (int mt = 0; mt < 4; ++mt)
            #pragma unroll
            for (int nt = 0; nt < 4; ++nt)
                acc[mt][nt] = MFMA16(af[mt], bf_[nt], acc[mt][nt]);
    }
}

// QKV GEMM: xb[4096][1024] @ Wt[3072][1024]^T. Epilogue scatters:
// cols 0..1023 -> Qb (x 0.125*log2e), 1024..2047 -> Kb, 2048..3071 -> Vt
// transposed [b,h,d,l] with l column-permuted within each 64-block:
// group g=(l>>2)&15 -> (g&8)*4 + (g&3)*8 + (g&4)  (PV b128 frags).
__global__ __launch_bounds__(256) void qkv_gemm(
    const u16* __restrict__ xb, const u16* __restrict__ Wt,
    const float* __restrict__ bqk, const float* __restrict__ bv,
    u16* __restrict__ Qb, u16* __restrict__ Kb, u16* __restrict__ Vt)
{
    __shared__ __align__(16) u16 As[128 * 32];
    __shared__ __align__(16) u16 Bs[128 * 32];
    const int t = threadIdx.x;
    const size_t m0 = blockIdx.y * 128, n0 = blockIdx.x * 128;
    f32x4 acc[4][4] = {};
    gemm_loop(xb, Wt, m0, n0, As, Bs, t, acc);

    const int w = t >> 6, lane = t & 63, ml = lane & 15, quad = lane >> 4;
    const int mw = (w >> 1) * 64, nw = (w & 1) * 64;
    const int seg = (int)(n0 >> 10);                   // 0=Q 1=K 2=V (block-uniform)

    #pragma unroll
    for (int mt = 0; mt < 4; ++mt) {
        #pragma unroll
        for (int nt = 0; nt < 4; ++nt) {
            f32x4 a = acc[mt][nt];
            int c = (int)n0 + nw + nt * 16 + ml;
            int mbase = (int)m0 + mw + mt * 16 + quad * 4;
            if (seg == 2) {
                int cv = c - 2048, h = cv >> 6, d = cv & 63;
                float bias = bv[cv];
                int bb = mbase >> 11, l0 = mbase & (L_ - 1);
                int g = (l0 >> 2) & 15;
                int col = (l0 & ~63) + ((g & 8) << 2) + ((g & 3) << 3) + (g & 4);
                ushort4 pk;
                pk.x = f2bf(a[0] + bias); pk.y = f2bf(a[1] + bias);
                pk.z = f2bf(a[2] + bias); pk.w = f2bf(a[3] + bias);
                *(ushort4*)&Vt[(((size_t)(bb * H_ + h)) * D_ + d) * L_ + col] = pk;
            } else {
                float bias = bqk[c];
                // Q scale: 1/sqrt(64) * log2(e)  (attn uses exp2)
                float sc = (seg == 0) ? 0.1803368801111244f : 1.0f;
                u16* dst = (seg == 0) ? Qb : Kb;
                int cc = c & 1023, h = cc >> 6, d = cc & 63;
                #pragma unroll
                for (int reg = 0; reg < 4; ++reg) {
                    int m = mbase + reg, bb = m >> 11, l = m & (L_ - 1);
                    dst[(((size_t)(bb * H_ + h)) * L_ + l) * D_ + d] = f2bf((a[reg] + bias) * sc);
                }
            }
        }
    }
}

// out GEMM: 64x128 tiles (grid 512 = 2 blocks/CU).
__global__ __launch_bounds__(256) void out_gemm(
    const u16* __restrict__ Ob, const u16* __restrict__ Wot,
    const float* __restrict__ bo, float* __restrict__ out)
{
    __shared__ __align__(16) u16 As[64 * 32];
    __shared__ __align__(16) u16 Bs[128 * 32];
    const int t = threadIdx.x, w = t >> 6, lane = t & 63;
    const int ml = lane & 15, quad = lane >> 4;
    const int mw = (w >> 1) * 32, nw = (w & 1) * 64;
    const size_t m0 = blockIdx.y * 64, n0 = blockIdx.x * 128;
    const int srow = lane >> 2, schunk = (lane & 3) * 8;

    f32x4 acc[2][4] = {};
    for (int k0 = 0; k0 < 1024; k0 += 32) {
        __syncthreads();
        {
            int row = w * 16 + srow;
            glds16(Ob + (m0 + row) * 1024 + k0 + schunk, As + (w * 16) * 32);
        }
        #pragma unroll
        for (int i = 0; i < 2; ++i) {
            int row = w * 32 + i * 16 + srow;
            glds16(Wot + (n0 + row) * 1024 + k0 + schunk, Bs + (w * 32 + i * 16) * 32);
        }
        __syncthreads();
        bf16x8 af[2], bf_[4];
        #pragma unroll
        for (int mt = 0; mt < 2; ++mt)
            af[mt] = *(const bf16x8*)(As + (mw + mt * 16 + ml) * 32 + quad * 8);
        #pragma unroll
        for (int nt = 0; nt < 4; ++nt)
            bf_[nt] = *(const bf16x8*)(Bs + (nw + nt * 16 + ml) * 32 + quad * 8);
        #pragma unroll
        for (int mt = 0; mt < 2; ++mt)
            #pragma unroll
            for (int nt = 0; nt < 4; ++nt)
                acc[mt][nt] = MFMA16(af[mt], bf_[nt], acc[mt][nt]);
    }

    #pragma unroll
    for (int mt = 0; mt < 2; ++mt)
        #pragma unroll
        for (int nt = 0; nt < 4; ++nt) {
            int c = (int)n0 + nw + nt * 16 + ml;
            int mbase = (int)m0 + mw + mt * 16 + quad * 4;
            float bias = bo[c];
            #pragma unroll
            for (int reg = 0; reg < 4; ++reg)
                out[(size_t)(mbase + reg) * F_ + c] = acc[mt][nt][reg] + bias;
        }
}

// ---------------------------------------------------------------------------
// Attention (r7 v4, verbatim): in-block split-K. Block = 4 waves x 64 queries.
//   wave w: half = w>>1 (keys half*1024..+1023), qsel = w&1 (queries qt*128+qsel*64).
// Per 64-key iter: S^T = K*Q^T (C: key=quad*4+r, query=ml); P = exp2(S^T)
// in-register == PV A-frag; V (pre-permuted) B-frag = single b128 from LDS;
// psum via ones-column MFMA -> C-layout-aligned normalization, no shuffles.
// Upper half's unnormalized O+psum combine additively through LDS (no-max
// softmax partials are pure sums). One barrier/iter, dbuf glds16 staging.
// ---------------------------------------------------------------------------
__global__ __launch_bounds__(256, 2) void attn_mfma(
    const u16* __restrict__ Qb, const u16* __restrict__ Kb,
    const u16* __restrict__ Vt, const u16* __restrict__ Ob_unused, u16* __restrict__ Ob)
{
    __shared__ __align__(16) u16 smem[32768];          // 64 KB: K[2][2][4096] | V[2][2][4096]

    const int t = threadIdx.x, w = t >> 6, lane = t & 63;
    const int ml = lane & 15, quad = lane >> 4;
    const int half = w >> 1, qsel = w & 1;
    const int qt = blockIdx.x, h = blockIdx.y, b = blockIdx.z;
    const int qbase = qt * 128 + qsel * 64;
    const size_t hoff = ((size_t)(b * H_ + h)) * L_ * D_;
    const u16* Qg = Qb + hoff;
    const u16* Kg = Kb + hoff;
    const u16* Vg = Vt + hoff;                         // [d][l_perm], ld = 2048

    u16* Kbuf = smem + half * 8192;                    // [dbuf][4096]
    u16* Vbuf = smem + 16384 + half * 8192;

    // Q fragments (B-operand of S^T), hoisted: lane ml = query row
    bf16x8 qf[4][2];
    #pragma unroll
    for (int m2 = 0; m2 < 4; ++m2)
        #pragma unroll
        for (int k2 = 0; k2 < 2; ++k2)
            qf[m2][k2] = *(const bf16x8*)(Qg + (size_t)(qbase + m2 * 16 + ml) * 64 + k2 * 32 + quad * 8);

    const int srow = lane >> 3, sch = lane & 7;
    auto stage = [&](int i, int d) {                   // pair stages its key tile
        int kt = half * 16 + i;
        #pragma unroll
        for (int ii = 0; ii < 4; ++ii) {
            int row = qsel * 32 + ii * 8 + srow;       // each wave: 32 rows
            int ch = sch ^ (row & 7);
            glds16(Kg + (size_t)(kt * 64 + row) * 64 + ch * 8, Kbuf + d * 4096 + (qsel * 32 + ii * 8) * 64);
            glds16(Vg + (size_t)row * L_ + kt * 64 + ch * 8,   Vbuf + d * 4096 + (qsel * 32 + ii * 8) * 64);
        }
    };

    bf16x8 vone;
    #pragma unroll
    for (int j = 0; j < 8; ++j) vone[j] = (__bf16)1.0f;

    f32x4 oacc[4][5] = {};                             // [m2][dt0..3, psum]

    stage(0, 0);
    for (int i = 0; i < 16; ++i) {
        __syncthreads();                               // drains prefetch + prev readers
        if (i < 15) stage(i + 1, (i + 1) & 1);

        const u16* Kl = Kbuf + (i & 1) * 4096;
        const u16* Vl = Vbuf + (i & 1) * 4096;
        bf16x8 kf[4][2], vf[4][2];
        #pragma unroll
        for (int t4 = 0; t4 < 4; ++t4) {
            int row = t4 * 16 + ml;
            #pragma unroll
            for (int k2 = 0; k2 < 2; ++k2)
                kf[t4][k2] = *(const bf16x8*)(Kl + row * 64 + (((k2 * 4 + quad) ^ (row & 7)) << 3));
        }
        #pragma unroll
        for (int dt = 0; dt < 4; ++dt) {
            int row = dt * 16 + ml;
            #pragma unroll
            for (int tp = 0; tp < 2; ++tp)
                vf[dt][tp] = *(const bf16x8*)(Vl + row * 64 + (((tp * 4 + quad) ^ (row & 7)) << 3));
        }

        #pragma unroll
        for (int m2 = 0; m2 < 4; ++m2) {
            f32x4 sacc[4] = {};
            #pragma unroll
            for (int k2 = 0; k2 < 2; ++k2)
                #pragma unroll
                for (int t4 = 0; t4 < 4; ++t4)
                    sacc[t4] = MFMA16(kf[t4][k2], qf[m2][k2], sacc[t4]);

            bf16x8 ap[2];
            #pragma unroll
            for (int t4 = 0; t4 < 4; ++t4)
                #pragma unroll
                for (int r = 0; r < 4; ++r)
                    ap[t4 >> 1][(t4 & 1) * 4 + r] = (__bf16)exp2f(sacc[t4][r]);

            #pragma unroll
            for (int tp = 0; tp < 2; ++tp) {
                #pragma unroll
                for (int dt = 0; dt < 4; ++dt)
                    oacc[m2][dt] = MFMA16(ap[tp], vf[dt][tp], oacc[m2][dt]);
                oacc[m2][4] = MFMA16(ap[tp], vone, oacc[m2][4]);   // row sums
            }
        }
    }

    // combine halves through LDS (pure additive: no-max softmax partials)
    __syncthreads();
    float* Fb = (float*)smem;                          // 40 chunks x 64 lanes x f32x4 = 40 KB
    if (half == 1) {
        #pragma unroll
        for (int m2 = 0; m2 < 4; ++m2)
            #pragma unroll
            for (int f = 0; f < 5; ++f)
                *(f32x4*)&Fb[(((qsel * 4 + m2) * 5 + f) * 64 + lane) * 4] = oacc[m2][f];
    }
    __syncthreads();
    if (half == 0) {
        #pragma unroll
        for (int m2 = 0; m2 < 4; ++m2)
            #pragma unroll
            for (int f = 0; f < 5; ++f)
                oacc[m2][f] += *(const f32x4*)&Fb[(((qsel * 4 + m2) * 5 + f) * 64 + lane) * 4];

        #pragma unroll
        for (int m2 = 0; m2 < 4; ++m2)
            #pragma unroll
            for (int r = 0; r < 4; ++r) {
                float il = 1.0f / oacc[m2][4][r];      // psum, layout-aligned
                int row = b * L_ + qbase + m2 * 16 + quad * 4 + r;
                #pragma unroll
                for (int dt = 0; dt < 4; ++dt) {
                    int c = h * 64 + dt * 16 + ml;
                    Ob[(size_t)row * F_ + c] = f2bf(oacc[m2][dt][r] * il);
                }
            }
    }
}

// ---------------------------------------------------------------------------
extern "C" void kernel_launch(void* const* d_in, const int* in_sizes, int n_in,
                              void* d_out, int out_size, void* d_ws, size_t ws_size,
                              hipStream_t stream)
{
    const float* x   = (const float*)d_in[0];
    const float* Wqk = (const float*)d_in[1];
    const float* bqk = (const float*)d_in[2];
    const float* Wv  = (const float*)d_in[3];
    const float* bv  = (const float*)d_in[4];
    const float* Wo  = (const float*)d_in[5];
    const float* bo  = (const float*)d_in[6];
    // d_in[7] = R: unused (LSH sort is a mathematical no-op).
    (void)in_sizes; (void)n_in; (void)out_size; (void)ws_size;
    float* out = (float*)d_out;

    u16* w16 = (u16*)d_ws;
    u16* xb  = w16;                   // 4096*1024
    u16* Wt  = xb  + 4194304;         // 3072*1024  (Wqk^T | Wv^T)
    u16* Wot = Wt  + 3145728;         // 1024*1024
    u16* Qb  = Wot + 1048576;         // [b,h,l,d]  (x 0.125*log2e)
    u16* Kb  = Qb  + 4194304;         // [b,h,l,d]
    u16* Vtw = Kb  + 4194304;         // [b,h,d,l_perm64]
    u16* Ob  = Vtw + 4194304;         // [4096][1024]

    prep<<<dim3(64, 32, 4), 256, 0, stream>>>(x, Wqk, Wv, Wo, xb, Wt, Wot);
    qkv_gemm<<<dim3(24, 32), 256, 0, stream>>>(xb, Wt, bqk, bv, Qb, Kb, Vtw);
    attn_mfma<<<dim3(16, 16, 2), 256, 0, stream>>>(Qb, Kb, Vtw, nullptr, Ob);
    out_gemm<<<dim3(8, 64), 256, 0, stream>>>(Ob, Wot, bo, out);
}